// Round 5
// baseline (298.587 us; speedup 1.0000x reference)
//
#include <hip/hip_runtime.h>
#include <cstdint>
#include <cstddef>

typedef unsigned short u16;
typedef __bf16 bf16x8 __attribute__((ext_vector_type(8)));
typedef float f32x4 __attribute__((ext_vector_type(4)));
typedef u16 u16x4 __attribute__((ext_vector_type(4)));
typedef u16 u16x8 __attribute__((ext_vector_type(8)));
typedef unsigned int u32x4 __attribute__((ext_vector_type(4)));

#define DEV __device__ __forceinline__

DEV u16 f2bf(float f) {
    union { float f; unsigned u; } un; un.f = f;
    unsigned u = un.u;
    return (u16)((u + 0x7fffu + ((u >> 16) & 1u)) >> 16);
}

DEV f32x4 mfma16(bf16x8 a, bf16x8 b, f32x4 c) {
    return __builtin_amdgcn_mfma_f32_16x16x32_bf16(a, b, c, 0, 0, 0);
}

// async global->LDS, 16B per lane; lds dest is wave-uniform base (+lane*16 implicit)
DEV void async16(const u16* g, u16* l) {
    __builtin_amdgcn_global_load_lds(
        (__attribute__((address_space(1))) unsigned int*)(void*)g,
        (__attribute__((address_space(3))) unsigned int*)(void*)l,
        16, 0, 0);
}

// ---------------- dtype detector ----------------
// fp32 buffers: low mantissa half-words have ~uniform exponent fields -> ~37% of
// words have exp>=160. bf16 N(0,~1): exponent <= ~130 always. flag=1 => fp32.
__global__ __launch_bounds__(256)
void detect_k(const u16* __restrict__ buf, int* __restrict__ flag) {
    __shared__ int red[256];
    const int tid = threadIdx.x;
    int cnt = 0;
    for (int i = 0; i < 16; ++i) {
        u16 w = buf[tid * 16 + i];
        int e = (w >> 7) & 0xFF;
        cnt += (e >= 160);
    }
    red[tid] = cnt;
    __syncthreads();
    for (int s = 128; s > 0; s >>= 1) {
        if (tid < s) red[tid] += red[tid + s];
        __syncthreads();
    }
    if (tid == 0) *flag = (red[0] > 16) ? 1 : 0;
}

// ---------------- src (fp32 or bf16, per flag) -> bf16 dst, 8 elems/thread ----------------
__global__ __launch_bounds__(256)
void cvt_any_k(const void* __restrict__ src, u16* __restrict__ dst,
               const int* __restrict__ flag, int n8) {
    int i = blockIdx.x * 256 + threadIdx.x;
    if (i >= n8) return;
    u16x8 o;
    if (*flag) {
        const float* s = (const float*)src + (size_t)i * 8;
        f32x4 a = *(const f32x4*)s;
        f32x4 b = *(const f32x4*)(s + 4);
        o[0] = f2bf(a[0]); o[1] = f2bf(a[1]); o[2] = f2bf(a[2]); o[3] = f2bf(a[3]);
        o[4] = f2bf(b[0]); o[5] = f2bf(b[1]); o[6] = f2bf(b[2]); o[7] = f2bf(b[3]);
    } else {
        o = *(const u16x8*)((const u16*)src + (size_t)i * 8);
    }
    *(u16x8*)(dst + (size_t)i * 8) = o;
}

// ---------------- src[R][C] (fp32 or bf16) -> bf16 dst[C][R] ----------------
__global__ __launch_bounds__(256)
void transpose_any_k(const void* __restrict__ src, u16* __restrict__ dst,
                     const int* __restrict__ flag, int R, int C) {
    __shared__ u16 t[64][65];
    const int tid = threadIdx.x;
    const int c0 = blockIdx.x * 64, r0 = blockIdx.y * 64;
    const bool isf32 = (*flag != 0);
    for (int i = 0; i < 4; ++i) {
        int e = (i * 256 + tid) * 4;
        int r = e >> 6, c = e & 63;
        if (isf32) {
            f32x4 v = *(const f32x4*)((const float*)src + (size_t)(r0 + r) * C + (c0 + c));
            t[r][c] = f2bf(v[0]); t[r][c + 1] = f2bf(v[1]);
            t[r][c + 2] = f2bf(v[2]); t[r][c + 3] = f2bf(v[3]);
        } else {
            u16x4 v = *(const u16x4*)((const u16*)src + (size_t)(r0 + r) * C + (c0 + c));
            t[r][c] = v[0]; t[r][c + 1] = v[1]; t[r][c + 2] = v[2]; t[r][c + 3] = v[3];
        }
    }
    __syncthreads();
    for (int i = 0; i < 4; ++i) {
        int e = (i * 256 + tid) * 4;
        int ro = e >> 6, co = e & 63;
        u16x4 v;
        v[0] = t[co][ro]; v[1] = t[co + 1][ro]; v[2] = t[co + 2][ro]; v[3] = t[co + 3][ro];
        *(u16x4*)(dst + (size_t)(c0 + ro) * R + (r0 + co)) = v;
    }
}

// ---------------- C[M][N] = A[M][K] @ Bt[N][K]^T, bf16 in, fp32 acc ----------------
// Output dtype: of32 ? fp32 : bf16 (wave-uniform branch).
// 128x128 tile, BK=32, 4 waves 2x2 (wave = 64x64 = 4x4 MFMA). LDS 16B chunks
// XOR-swizzled: chunk kc of row at slot kc ^ ((row>>1)&3).
__global__ __launch_bounds__(256, 2)
void gemm_bt(const u16* __restrict__ A, const u16* __restrict__ Bt,
             void* __restrict__ Cout, int M, int N, int K, int lda, int of32) {
    __shared__ alignas(16) u16 As[128 * 32];
    __shared__ alignas(16) u16 Bs[128 * 32];
    const int tid = threadIdx.x;
    const int wave = tid >> 6, lane = tid & 63;
    const int quad = lane >> 4, l16 = lane & 15;
    const int m0 = blockIdx.x * 128, n0 = blockIdx.y * 128;
    const int wm = (wave & 1) * 64, wn = (wave >> 1) * 64;

    const f32x4 zero = {0.f, 0.f, 0.f, 0.f};
    f32x4 acc[4][4];
    for (int i = 0; i < 4; ++i) for (int j = 0; j < 4; ++j) acc[i][j] = zero;

    for (int k0 = 0; k0 < K; k0 += 32) {
        __syncthreads();
        for (int p = 0; p < 2; ++p) {
            int s = p * 256 + tid;             // chunk slot 0..511
            int row = s >> 2, kcs = s & 3;
            int kc = kcs ^ ((row >> 1) & 3);
            async16(A + (size_t)(m0 + row) * lda + k0 + kc * 8, &As[(p * 256 + wave * 64) * 8]);
            async16(Bt + (size_t)(n0 + row) * K + k0 + kc * 8, &Bs[(p * 256 + wave * 64) * 8]);
        }
        __syncthreads();

        bf16x8 af[4], bfr[4];
        for (int mt = 0; mt < 4; ++mt) {
            int row = wm + mt * 16 + l16;
            int ci = (row << 2) | (quad ^ ((row >> 1) & 3));
            af[mt] = *(const bf16x8*)&As[ci * 8];
        }
        for (int nt = 0; nt < 4; ++nt) {
            int col = wn + nt * 16 + l16;
            int ci = (col << 2) | (quad ^ ((col >> 1) & 3));
            bfr[nt] = *(const bf16x8*)&Bs[ci * 8];
        }
        for (int mt = 0; mt < 4; ++mt)
            for (int nt = 0; nt < 4; ++nt)
                acc[mt][nt] = mfma16(af[mt], bfr[nt], acc[mt][nt]);
    }

    for (int mt = 0; mt < 4; ++mt)
        for (int r = 0; r < 4; ++r) {
            int row = m0 + wm + mt * 16 + quad * 4 + r;
            if (of32) {
                float* crow = (float*)Cout + (size_t)row * N + n0 + wn + l16;
                for (int nt = 0; nt < 4; ++nt)
                    crow[nt * 16] = acc[mt][nt][r];
            } else {
                u16* crow = (u16*)Cout + (size_t)row * N + n0 + wn + l16;
                for (int nt = 0; nt < 4; ++nt)
                    crow[nt * 16] = f2bf(acc[mt][nt][r]);
            }
        }
}

// ---------------- flash attention, causal + ALiBi (bias = slope_h * key_pos) ----------------
// qkv: [4096][3072] bf16 (Q=cols 0..1023, K=1024..2047, V=2048..3071; feat=h*64+d).
// Output written in-place into the Q region: block (qb,b,h) loads its own Q slice into
// registers before the K-loop and is the only writer of that slice. o == qkv.
__global__ __launch_bounds__(256, 2)
void attn_k(const u16* qkv, u16* o, int ostride) {
    __shared__ alignas(16) u16 Ks [64 * 72];
    __shared__ alignas(16) u16 Vts[64 * 72];
    __shared__ alignas(16) u16 Ps [128 * 72];
    const int x = blockIdx.x;
    const int qb = (x & 1) ? (15 - (x >> 1)) : (x >> 1);
    const int bh = blockIdx.y;
    const int b = bh >> 4, h = bh & 15;
    const int tid = threadIdx.x;
    const int wave = tid >> 6, lane = tid & 63;
    const int quad = lane >> 4, l16 = lane & 15;
    const float slope = exp2f(-0.5f * (float)(h + 1));
    const size_t seq0 = (size_t)b * 2048;

    bf16x8 qf[2][2];
    for (int mt = 0; mt < 2; ++mt) {
        size_t t = seq0 + qb * 128 + wave * 32 + mt * 16 + l16;
        const u16* qrow = qkv + t * 3072 + h * 64;
        for (int ks = 0; ks < 2; ++ks)
            qf[mt][ks] = *(const bf16x8*)(qrow + ks * 32 + quad * 8);
    }

    float mst[2][4], lst[2][4];
    f32x4 oacc[2][4];
    const f32x4 zero = {0.f, 0.f, 0.f, 0.f};
    for (int mt = 0; mt < 2; ++mt)
        for (int r = 0; r < 4; ++r) { mst[mt][r] = -1e30f; lst[mt][r] = 0.f; }
    for (int mt = 0; mt < 2; ++mt) for (int nt = 0; nt < 4; ++nt) oacc[mt][nt] = zero;

    const int ktiles = 2 * qb + 2;
    for (int kt = 0; kt < ktiles; ++kt) {
        for (int it = 0; it < 2; ++it) {
            int c = it * 256 + tid;
            int key = c >> 3, off = (c & 7) * 8;
            const u16* src = qkv + (seq0 + kt * 64 + key) * 3072 + 1024 + h * 64 + off;
            *(u32x4*)&Ks[key * 72 + off] = *(const u32x4*)src;
        }
        for (int it = 0; it < 2; ++it) {
            int c = it * 256 + tid;
            int key = c & 63, d0 = (c >> 6) * 8;
            const u16* src = qkv + (seq0 + kt * 64 + key) * 3072 + 2048 + h * 64 + d0;
            u16x8 v = *(const u16x8*)src;
            for (int j = 0; j < 8; ++j) Vts[(d0 + j) * 72 + key] = v[j];
        }
        __syncthreads();

        f32x4 s[2][4];
        for (int mt = 0; mt < 2; ++mt) for (int nt = 0; nt < 4; ++nt) s[mt][nt] = zero;
        for (int nt = 0; nt < 4; ++nt)
            for (int ks = 0; ks < 2; ++ks) {
                bf16x8 bk = *(const bf16x8*)&Ks[(nt * 16 + l16) * 72 + ks * 32 + quad * 8];
                for (int mt = 0; mt < 2; ++mt)
                    s[mt][nt] = mfma16(qf[mt][ks], bk, s[mt][nt]);
            }

        for (int mt = 0; mt < 2; ++mt) {
            int ibase = qb * 128 + wave * 32 + mt * 16 + quad * 4;
            for (int r = 0; r < 4; ++r) {
                int i = ibase + r;
                float best = -1e30f;
                for (int nt = 0; nt < 4; ++nt) {
                    int j = kt * 64 + nt * 16 + l16;
                    float v = s[mt][nt][r] * 0.125f + slope * (float)j;
                    v = (j <= i) ? v : -1e30f;
                    s[mt][nt][r] = v;
                    best = fmaxf(best, v);
                }
                for (int d = 1; d < 16; d <<= 1) best = fmaxf(best, __shfl_xor(best, d, 16));
                float mnew = fmaxf(mst[mt][r], best);
                float alpha = __expf(mst[mt][r] - mnew);
                mst[mt][r] = mnew;
                float psum = 0.f;
                for (int nt = 0; nt < 4; ++nt) {
                    float p = __expf(s[mt][nt][r] - mnew);
                    s[mt][nt][r] = p;
                    psum += p;
                }
                for (int d = 1; d < 16; d <<= 1) psum += __shfl_xor(psum, d, 16);
                lst[mt][r] = lst[mt][r] * alpha + psum;
                for (int nt = 0; nt < 4; ++nt) oacc[mt][nt][r] *= alpha;
                int rowl = wave * 32 + mt * 16 + quad * 4 + r;
                for (int nt = 0; nt < 4; ++nt)
                    Ps[rowl * 72 + nt * 16 + l16] = f2bf(s[mt][nt][r]);
            }
        }

        __syncthreads();

        for (int nt = 0; nt < 4; ++nt)
            for (int ks = 0; ks < 2; ++ks) {
                bf16x8 bv = *(const bf16x8*)&Vts[(nt * 16 + l16) * 72 + ks * 32 + quad * 8];
                for (int mt = 0; mt < 2; ++mt) {
                    bf16x8 ap = *(const bf16x8*)&Ps[(wave * 32 + mt * 16 + l16) * 72 + ks * 32 + quad * 8];
                    oacc[mt][nt] = mfma16(ap, bv, oacc[mt][nt]);
                }
            }
        __syncthreads();
    }

    for (int mt = 0; mt < 2; ++mt)
        for (int r = 0; r < 4; ++r) {
            int il = qb * 128 + wave * 32 + mt * 16 + quad * 4 + r;
            float inv = 1.f / lst[mt][r];
            u16* orow = o + (seq0 + il) * (size_t)ostride + h * 64 + l16;
            for (int nt = 0; nt < 4; ++nt)
                orow[nt * 16] = f2bf(oacc[mt][nt][r] * inv);
        }
}

// ---------------- launch ----------------
// Inputs fp32 (detector-confirmed R3/R4), OUTPUT fp32 (reference dtype — the R1
// "bf16 output" inference was a misread of the harness source in the traceback).
// Workspace (peak 30 MiB): flags(256B) | wqkvT 6 MiB (reused for wprojT) | qkv 24 MiB.
// x's bf16 copy uses the first 8 MiB of d_out (16 MiB fp32) — dead before gemm2 writes.
extern "C" void kernel_launch(void* const* d_in, const int* in_sizes, int n_in,
                              void* d_out, int out_size, void* d_ws, size_t ws_size,
                              hipStream_t stream) {
    (void)in_sizes; (void)n_in; (void)out_size; (void)ws_size;
    const void* x     = d_in[0];   // [4096][1024] fp32
    const void* wqkv  = d_in[1];   // [1024][3072] fp32
    const void* wproj = d_in[2];   // [1024][1024] fp32

    char* ws = (char*)d_ws;
    int* flags  = (int*)ws;
    u16* wqkvT  = (u16*)(ws + 256);                          // 6 MiB
    u16* wprojT = wqkvT;                                     // reused after gemm1
    u16* qkv    = wqkvT + (size_t)3072 * 1024;               // 24 MiB
    u16* xb     = (u16*)d_out;                               // scratch in d_out

    detect_k<<<dim3(1), 256, 0, stream>>>((const u16*)x,     flags + 0);
    detect_k<<<dim3(1), 256, 0, stream>>>((const u16*)wqkv,  flags + 1);
    detect_k<<<dim3(1), 256, 0, stream>>>((const u16*)wproj, flags + 2);

    cvt_any_k<<<dim3(2048), 256, 0, stream>>>(x, xb, flags + 0, 4096 * 1024 / 8);
    transpose_any_k<<<dim3(48, 16), 256, 0, stream>>>(wqkv, wqkvT, flags + 1, 1024, 3072);

    gemm_bt<<<dim3(32, 24), 256, 0, stream>>>(xb, wqkvT, qkv, 4096, 3072, 1024, 1024, 0);

    transpose_any_k<<<dim3(16, 16), 256, 0, stream>>>(wproj, wprojT, flags + 2, 1024, 1024);

    attn_k<<<dim3(16, 32), 256, 0, stream>>>(qkv, qkv, 3072);   // output -> Q region

    gemm_bt<<<dim3(32, 8), 256, 0, stream>>>(qkv, wprojT, d_out, 4096, 1024, 1024, 3072, 1);
}

// Round 6
// 280.025 us; speedup vs baseline: 1.0663x; 1.0663x over previous
//
#include <hip/hip_runtime.h>
#include <cstdint>
#include <cstddef>

typedef unsigned short u16;
typedef __bf16 bf16x8 __attribute__((ext_vector_type(8)));
typedef float f32x4 __attribute__((ext_vector_type(4)));
typedef u16 u16x4 __attribute__((ext_vector_type(4)));
typedef u16 u16x8 __attribute__((ext_vector_type(8)));
typedef unsigned int u32x4 __attribute__((ext_vector_type(4)));

#define DEV __device__ __forceinline__

DEV u16 f2bf(float f) {
    union { float f; unsigned u; } un; un.f = f;
    unsigned u = un.u;
    return (u16)((u + 0x7fffu + ((u >> 16) & 1u)) >> 16);
}

DEV u16 bf16c(float f) {            // HW convert (RNE), 1 instr on gfx950
    __bf16 b = (__bf16)f;
    u16 r; __builtin_memcpy(&r, &b, 2); return r;
}

DEV f32x4 mfma16(bf16x8 a, bf16x8 b, f32x4 c) {
    return __builtin_amdgcn_mfma_f32_16x16x32_bf16(a, b, c, 0, 0, 0);
}

// async global->LDS, 16B per lane; lds dest is wave-uniform base (+lane*16 implicit)
DEV void async16(const u16* g, u16* l) {
    __builtin_amdgcn_global_load_lds(
        (__attribute__((address_space(1))) unsigned int*)(void*)g,
        (__attribute__((address_space(3))) unsigned int*)(void*)l,
        16, 0, 0);
}

// ---------------- fp32 -> bf16 cast (x), 8 elems/thread ----------------
__global__ __launch_bounds__(256)
void cvt_k(const float* __restrict__ src, u16* __restrict__ dst, int n8) {
    int i = blockIdx.x * 256 + threadIdx.x;
    if (i >= n8) return;
    const float* s = src + (size_t)i * 8;
    f32x4 a = *(const f32x4*)s;
    f32x4 b = *(const f32x4*)(s + 4);
    u16x8 o;
    o[0] = f2bf(a[0]); o[1] = f2bf(a[1]); o[2] = f2bf(a[2]); o[3] = f2bf(a[3]);
    o[4] = f2bf(b[0]); o[5] = f2bf(b[1]); o[6] = f2bf(b[2]); o[7] = f2bf(b[3]);
    *(u16x8*)(dst + (size_t)i * 8) = o;
}

// ---------------- fp32 src[R][C] -> bf16 dst[C][R] ----------------
__global__ __launch_bounds__(256)
void transpose_cvt_k(const float* __restrict__ src, u16* __restrict__ dst, int R, int C) {
    __shared__ u16 t[64][65];
    const int tid = threadIdx.x;
    const int c0 = blockIdx.x * 64, r0 = blockIdx.y * 64;
    for (int i = 0; i < 4; ++i) {
        int e = (i * 256 + tid) * 4;
        int r = e >> 6, c = e & 63;
        f32x4 v = *(const f32x4*)(src + (size_t)(r0 + r) * C + (c0 + c));
        t[r][c] = f2bf(v[0]); t[r][c + 1] = f2bf(v[1]);
        t[r][c + 2] = f2bf(v[2]); t[r][c + 3] = f2bf(v[3]);
    }
    __syncthreads();
    for (int i = 0; i < 4; ++i) {
        int e = (i * 256 + tid) * 4;
        int ro = e >> 6, co = e & 63;
        u16x4 v;
        v[0] = t[co][ro]; v[1] = t[co + 1][ro]; v[2] = t[co + 2][ro]; v[3] = t[co + 3][ro];
        *(u16x4*)(dst + (size_t)(c0 + ro) * R + (r0 + co)) = v;
    }
}

// ---------------- C[M][N] = A[M][K] @ Bt[N][K]^T, bf16 in, fp32 acc ----------------
// Output dtype: of32 ? fp32 : bf16. 128x128 tile, BK=32, 4 waves 2x2.
// LDS 16B chunks XOR-swizzled: chunk kc of row at slot kc ^ ((row>>1)&3).
__global__ __launch_bounds__(256, 2)
void gemm_bt(const u16* __restrict__ A, const u16* __restrict__ Bt,
             void* __restrict__ Cout, int M, int N, int K, int lda, int of32) {
    __shared__ alignas(16) u16 As[128 * 32];
    __shared__ alignas(16) u16 Bs[128 * 32];
    const int tid = threadIdx.x;
    const int wave = tid >> 6, lane = tid & 63;
    const int quad = lane >> 4, l16 = lane & 15;
    const int m0 = blockIdx.x * 128, n0 = blockIdx.y * 128;
    const int wm = (wave & 1) * 64, wn = (wave >> 1) * 64;

    const f32x4 zero = {0.f, 0.f, 0.f, 0.f};
    f32x4 acc[4][4];
    for (int i = 0; i < 4; ++i) for (int j = 0; j < 4; ++j) acc[i][j] = zero;

    for (int k0 = 0; k0 < K; k0 += 32) {
        __syncthreads();
        for (int p = 0; p < 2; ++p) {
            int s = p * 256 + tid;             // chunk slot 0..511
            int row = s >> 2, kcs = s & 3;
            int kc = kcs ^ ((row >> 1) & 3);
            async16(A + (size_t)(m0 + row) * lda + k0 + kc * 8, &As[(p * 256 + wave * 64) * 8]);
            async16(Bt + (size_t)(n0 + row) * K + k0 + kc * 8, &Bs[(p * 256 + wave * 64) * 8]);
        }
        __syncthreads();

        bf16x8 af[4], bfr[4];
        for (int mt = 0; mt < 4; ++mt) {
            int row = wm + mt * 16 + l16;
            int ci = (row << 2) | (quad ^ ((row >> 1) & 3));
            af[mt] = *(const bf16x8*)&As[ci * 8];
        }
        for (int nt = 0; nt < 4; ++nt) {
            int col = wn + nt * 16 + l16;
            int ci = (col << 2) | (quad ^ ((col >> 1) & 3));
            bfr[nt] = *(const bf16x8*)&Bs[ci * 8];
        }
        for (int mt = 0; mt < 4; ++mt)
            for (int nt = 0; nt < 4; ++nt)
                acc[mt][nt] = mfma16(af[mt], bfr[nt], acc[mt][nt]);
    }

    for (int mt = 0; mt < 4; ++mt)
        for (int r = 0; r < 4; ++r) {
            int row = m0 + wm + mt * 16 + quad * 4 + r;
            if (of32) {
                float* crow = (float*)Cout + (size_t)row * N + n0 + wn + l16;
                for (int nt = 0; nt < 4; ++nt)
                    crow[nt * 16] = acc[mt][nt][r];
            } else {
                u16* crow = (u16*)Cout + (size_t)row * N + n0 + wn + l16;
                for (int nt = 0; nt < 4; ++nt)
                    crow[nt * 16] = f2bf(acc[mt][nt][r]);
            }
        }
}

// ---------------- flash attention, causal + ALiBi ----------------
// qkv: [4096][3072] bf16 (Q=0..1023, K=1024..2047, V=2048..3071; feat=h*64+d).
// 64-row Q-blocks, grid (32 qb, 32 bh), 4 waves (wave owns 16 rows).
// K/V double-buffered in LDS with register prefetch (loads for kt+1 issued at top
// of kt, LDS-published after PV) -> one barrier per kt, no global-load stall.
// Softmax in log2 domain (exp2 only); causal cmp only on the diagonal tile.
// Output in-place into the Q region (block reads its own Q before the loop).
__global__ __launch_bounds__(256, 3)
void attn_k(const u16* qkv, u16* o, int ostride) {
    __shared__ alignas(16) u16 KsB [2][64 * 72];
    __shared__ alignas(16) u16 VtsB[2][64 * 72];
    __shared__ alignas(16) u16 Psh [64 * 72];
    const int x = blockIdx.x;
    const int qb = (x & 1) ? (31 - (x >> 1)) : (x >> 1);   // pair heavy+light blocks
    const int bh = blockIdx.y;
    const int b = bh >> 4, h = bh & 15;
    const int tid = threadIdx.x;
    const int wave = tid >> 6, lane = tid & 63;
    const int quad = lane >> 4, l16 = lane & 15;
    const float LOG2E = 1.44269504f;
    const float slope2 = exp2f(-0.5f * (float)(h + 1)) * LOG2E;
    const float scale2 = 0.125f * LOG2E;
    const size_t seq0 = (size_t)b * 2048;
    const int row0 = qb * 64 + wave * 16;          // wave's first Q row (block-seq coords)

    // Q fragments in registers (A-layout: m=l16, k=quad*8+j)
    bf16x8 qf[2];
    {
        const u16* qrow = qkv + (seq0 + row0 + l16) * 3072 + h * 64;
        qf[0] = *(const bf16x8*)(qrow + quad * 8);
        qf[1] = *(const bf16x8*)(qrow + 32 + quad * 8);
    }

    float mst[4], lst[4];
    f32x4 oacc[4];
    const f32x4 zero = {0.f, 0.f, 0.f, 0.f};
    for (int r = 0; r < 4; ++r) { mst[r] = -1e30f; lst[r] = 0.f; }
    for (int nt = 0; nt < 4; ++nt) oacc[nt] = zero;

    const int ktiles = qb + 1;
    const int c0 = tid * 2;
    const u16* kb0 = qkv + seq0 * 3072 + 1024 + h * 64;

    // stage tile 0
    u16x8 kr[2], vr[2];
    for (int i = 0; i < 2; ++i) {
        int c = c0 + i;
        kr[i] = *(const u16x8*)(kb0 + (size_t)(c >> 3) * 3072 + (c & 7) * 8);
        vr[i] = *(const u16x8*)(kb0 + 1024 + (size_t)(c & 63) * 3072 + (c >> 6) * 8);
    }
    for (int i = 0; i < 2; ++i) {
        int c = c0 + i;
        *(u16x8*)&KsB[0][(c >> 3) * 72 + (c & 7) * 8] = kr[i];
        int key = c & 63, d0 = (c >> 6) * 8;
        for (int j = 0; j < 8; ++j) VtsB[0][(d0 + j) * 72 + key] = vr[i][j];
    }
    __syncthreads();

    for (int kt = 0; kt < ktiles; ++kt) {
        const int cur = kt & 1, nxt = cur ^ 1;
        const bool more = (kt + 1 < ktiles);
        if (more) {   // prefetch kt+1 into registers (lands during this iteration)
            const u16* kb = kb0 + (size_t)(kt + 1) * 64 * 3072;
            for (int i = 0; i < 2; ++i) {
                int c = c0 + i;
                kr[i] = *(const u16x8*)(kb + (size_t)(c >> 3) * 3072 + (c & 7) * 8);
                vr[i] = *(const u16x8*)(kb + 1024 + (size_t)(c & 63) * 3072 + (c >> 6) * 8);
            }
        }

        // S = Q @ K^T
        f32x4 s[4];
        for (int nt = 0; nt < 4; ++nt) s[nt] = zero;
        for (int nt = 0; nt < 4; ++nt)
            for (int ks = 0; ks < 2; ++ks) {
                bf16x8 bk = *(const bf16x8*)&KsB[cur][(nt * 16 + l16) * 72 + ks * 32 + quad * 8];
                s[nt] = mfma16(qf[ks], bk, s[nt]);
            }

        // bias + (diagonal-only) causal mask, log2 domain
        if (kt == qb) {
            const int irow = qb * 64 + wave * 16 + quad * 4;
            for (int nt = 0; nt < 4; ++nt) {
                int j = kt * 64 + nt * 16 + l16;
                float bias = slope2 * (float)j;
                for (int r = 0; r < 4; ++r) {
                    float v = s[nt][r] * scale2 + bias;
                    s[nt][r] = (j <= irow + r) ? v : -1e30f;
                }
            }
        } else {
            for (int nt = 0; nt < 4; ++nt) {
                float bias = slope2 * (float)(kt * 64 + nt * 16 + l16);
                for (int r = 0; r < 4; ++r)
                    s[nt][r] = s[nt][r] * scale2 + bias;
            }
        }

        // online softmax (C-layout row = quad*4+r); Ps write/read is intra-wave
        for (int r = 0; r < 4; ++r) {
            float best = fmaxf(fmaxf(s[0][r], s[1][r]), fmaxf(s[2][r], s[3][r]));
            for (int d = 1; d < 16; d <<= 1) best = fmaxf(best, __shfl_xor(best, d, 16));
            float mnew = fmaxf(mst[r], best);
            float alpha = exp2f(mst[r] - mnew);
            mst[r] = mnew;
            float psum = 0.f;
            for (int nt = 0; nt < 4; ++nt) {
                float p = exp2f(s[nt][r] - mnew);
                s[nt][r] = p;
                psum += p;
            }
            for (int d = 1; d < 16; d <<= 1) psum += __shfl_xor(psum, d, 16);
            lst[r] = lst[r] * alpha + psum;
            for (int nt = 0; nt < 4; ++nt) oacc[nt][r] *= alpha;
            int rowl = wave * 16 + quad * 4 + r;
            for (int nt = 0; nt < 4; ++nt)
                Psh[rowl * 72 + nt * 16 + l16] = bf16c(s[nt][r]);
        }

        // O += P @ V (A-frag of Psh: own wave's rows only -> no barrier needed;
        // DS pipe is in-order per wave, same-object deps block compiler reordering)
        for (int nt = 0; nt < 4; ++nt)
            for (int ks = 0; ks < 2; ++ks) {
                bf16x8 bv = *(const bf16x8*)&VtsB[cur][(nt * 16 + l16) * 72 + ks * 32 + quad * 8];
                bf16x8 ap = *(const bf16x8*)&Psh[(wave * 16 + l16) * 72 + ks * 32 + quad * 8];
                oacc[nt] = mfma16(ap, bv, oacc[nt]);
            }

        if (more) {   // publish kt+1 tiles into the other buffer
            for (int i = 0; i < 2; ++i) {
                int c = c0 + i;
                *(u16x8*)&KsB[nxt][(c >> 3) * 72 + (c & 7) * 8] = kr[i];
                int key = c & 63, d0 = (c >> 6) * 8;
                for (int j = 0; j < 8; ++j) VtsB[nxt][(d0 + j) * 72 + key] = vr[i][j];
            }
        }
        __syncthreads();   // publish nxt K/V; also separates Ps reuse across iters
    }

    for (int r = 0; r < 4; ++r) {
        int il = qb * 64 + wave * 16 + quad * 4 + r;
        float inv = 1.f / lst[r];
        u16* orow = o + (seq0 + il) * (size_t)ostride + h * 64 + l16;
        for (int nt = 0; nt < 4; ++nt)
            orow[nt * 16] = bf16c(oacc[nt][r] * inv);
    }
}

// ---------------- launch ----------------
// Inputs fp32 (confirmed R3-R5), output fp32. Workspace peak 30 MiB:
//   ws+256: wqkvT [3072][1024] bf16 6 MiB (reused for wprojT) | qkv [4096][3072] 24 MiB.
// x's bf16 copy uses the first 8 MiB of d_out (dead before gemm2 writes all 16 MiB).
extern "C" void kernel_launch(void* const* d_in, const int* in_sizes, int n_in,
                              void* d_out, int out_size, void* d_ws, size_t ws_size,
                              hipStream_t stream) {
    (void)in_sizes; (void)n_in; (void)out_size; (void)ws_size;
    const float* x     = (const float*)d_in[0];   // [4096][1024]
    const float* wqkv  = (const float*)d_in[1];   // [1024][3072]
    const float* wproj = (const float*)d_in[2];   // [1024][1024]

    char* ws = (char*)d_ws;
    u16* wqkvT  = (u16*)(ws + 256);
    u16* wprojT = wqkvT;                               // reused after gemm1
    u16* qkv    = wqkvT + (size_t)3072 * 1024;
    u16* xb     = (u16*)d_out;                         // scratch in d_out

    cvt_k<<<dim3(2048), 256, 0, stream>>>(x, xb, 4096 * 1024 / 8);
    transpose_cvt_k<<<dim3(48, 16), 256, 0, stream>>>(wqkv, wqkvT, 1024, 3072);

    gemm_bt<<<dim3(32, 24), 256, 0, stream>>>(xb, wqkvT, qkv, 4096, 3072, 1024, 1024, 0);

    transpose_cvt_k<<<dim3(16, 16), 256, 0, stream>>>(wproj, wprojT, 1024, 1024);

    attn_k<<<dim3(32, 32), 256, 0, stream>>>(qkv, qkv, 3072);   // out -> Q region

    gemm_bt<<<dim3(32, 8), 256, 0, stream>>>(qkv, wprojT, d_out, 4096, 1024, 1024, 3072, 1);
}

// Round 7
// 252.805 us; speedup vs baseline: 1.1811x; 1.1077x over previous
//
#include <hip/hip_runtime.h>
#include <cstdint>
#include <cstddef>

typedef unsigned short u16;
typedef __bf16 bf16x8 __attribute__((ext_vector_type(8)));
typedef float f32x4 __attribute__((ext_vector_type(4)));
typedef u16 u16x4 __attribute__((ext_vector_type(4)));
typedef u16 u16x8 __attribute__((ext_vector_type(8)));
typedef unsigned int u32x2 __attribute__((ext_vector_type(2)));
typedef unsigned int u32x4 __attribute__((ext_vector_type(4)));

#define DEV __device__ __forceinline__

DEV u16 f2bf(float f) {
    union { float f; unsigned u; } un; un.f = f;
    unsigned u = un.u;
    return (u16)((u + 0x7fffu + ((u >> 16) & 1u)) >> 16);
}

DEV u16 bf16c(float f) {            // HW convert (RNE), 1 instr on gfx950
    __bf16 b = (__bf16)f;
    u16 r; __builtin_memcpy(&r, &b, 2); return r;
}

DEV f32x4 mfma16(bf16x8 a, bf16x8 b, f32x4 c) {
    return __builtin_amdgcn_mfma_f32_16x16x32_bf16(a, b, c, 0, 0, 0);
}

DEV f32x4 vmax4(f32x4 a, f32x4 b) {
    f32x4 r;
    r[0] = fmaxf(a[0], b[0]); r[1] = fmaxf(a[1], b[1]);
    r[2] = fmaxf(a[2], b[2]); r[3] = fmaxf(a[3], b[3]);
    return r;
}

// async global->LDS, 16B per lane; lds dest is wave-uniform base (+lane*16 implicit)
DEV void async16(const u16* g, u16* l) {
    __builtin_amdgcn_global_load_lds(
        (__attribute__((address_space(1))) unsigned int*)(void*)g,
        (__attribute__((address_space(3))) unsigned int*)(void*)l,
        16, 0, 0);
}

// ---------------- fp32 -> bf16 cast (x), 8 elems/thread ----------------
__global__ __launch_bounds__(256)
void cvt_k(const float* __restrict__ src, u16* __restrict__ dst, int n8) {
    int i = blockIdx.x * 256 + threadIdx.x;
    if (i >= n8) return;
    const float* s = src + (size_t)i * 8;
    f32x4 a = *(const f32x4*)s;
    f32x4 b = *(const f32x4*)(s + 4);
    u16x8 o;
    o[0] = f2bf(a[0]); o[1] = f2bf(a[1]); o[2] = f2bf(a[2]); o[3] = f2bf(a[3]);
    o[4] = f2bf(b[0]); o[5] = f2bf(b[1]); o[6] = f2bf(b[2]); o[7] = f2bf(b[3]);
    *(u16x8*)(dst + (size_t)i * 8) = o;
}

// ---------------- fp32 src[R][C] -> bf16 dst[C][R] ----------------
__global__ __launch_bounds__(256)
void transpose_cvt_k(const float* __restrict__ src, u16* __restrict__ dst, int R, int C) {
    __shared__ u16 t[64][65];
    const int tid = threadIdx.x;
    const int c0 = blockIdx.x * 64, r0 = blockIdx.y * 64;
    for (int i = 0; i < 4; ++i) {
        int e = (i * 256 + tid) * 4;
        int r = e >> 6, c = e & 63;
        f32x4 v = *(const f32x4*)(src + (size_t)(r0 + r) * C + (c0 + c));
        t[r][c] = f2bf(v[0]); t[r][c + 1] = f2bf(v[1]);
        t[r][c + 2] = f2bf(v[2]); t[r][c + 3] = f2bf(v[3]);
    }
    __syncthreads();
    for (int i = 0; i < 4; ++i) {
        int e = (i * 256 + tid) * 4;
        int ro = e >> 6, co = e & 63;
        u16x4 v;
        v[0] = t[co][ro]; v[1] = t[co + 1][ro]; v[2] = t[co + 2][ro]; v[3] = t[co + 3][ro];
        *(u16x4*)(dst + (size_t)(c0 + ro) * R + (r0 + co)) = v;
    }
}

// ---------------- C[M][N] = A[M][K] @ Bt[N][K]^T, bf16 in, fp32 acc ----------------
// Output dtype: of32 ? fp32 : bf16. 128x128 tile, BK=32, 4 waves 2x2.
// LDS 16B chunks XOR-swizzled: chunk kc of row at slot kc ^ ((row>>1)&3).
__global__ __launch_bounds__(256, 2)
void gemm_bt(const u16* __restrict__ A, const u16* __restrict__ Bt,
             void* __restrict__ Cout, int M, int N, int K, int lda, int of32) {
    __shared__ alignas(16) u16 As[128 * 32];
    __shared__ alignas(16) u16 Bs[128 * 32];
    const int tid = threadIdx.x;
    const int wave = tid >> 6, lane = tid & 63;
    const int quad = lane >> 4, l16 = lane & 15;
    const int m0 = blockIdx.x * 128, n0 = blockIdx.y * 128;
    const int wm = (wave & 1) * 64, wn = (wave >> 1) * 64;

    const f32x4 zero = {0.f, 0.f, 0.f, 0.f};
    f32x4 acc[4][4];
    for (int i = 0; i < 4; ++i) for (int j = 0; j < 4; ++j) acc[i][j] = zero;

    for (int k0 = 0; k0 < K; k0 += 32) {
        __syncthreads();
        for (int p = 0; p < 2; ++p) {
            int s = p * 256 + tid;             // chunk slot 0..511
            int row = s >> 2, kcs = s & 3;
            int kc = kcs ^ ((row >> 1) & 3);
            async16(A + (size_t)(m0 + row) * lda + k0 + kc * 8, &As[(p * 256 + wave * 64) * 8]);
            async16(Bt + (size_t)(n0 + row) * K + k0 + kc * 8, &Bs[(p * 256 + wave * 64) * 8]);
        }
        __syncthreads();

        bf16x8 af[4], bfr[4];
        for (int mt = 0; mt < 4; ++mt) {
            int row = wm + mt * 16 + l16;
            int ci = (row << 2) | (quad ^ ((row >> 1) & 3));
            af[mt] = *(const bf16x8*)&As[ci * 8];
        }
        for (int nt = 0; nt < 4; ++nt) {
            int col = wn + nt * 16 + l16;
            int ci = (col << 2) | (quad ^ ((col >> 1) & 3));
            bfr[nt] = *(const bf16x8*)&Bs[ci * 8];
        }
        for (int mt = 0; mt < 4; ++mt)
            for (int nt = 0; nt < 4; ++nt)
                acc[mt][nt] = mfma16(af[mt], bfr[nt], acc[mt][nt]);
    }

    for (int mt = 0; mt < 4; ++mt)
        for (int r = 0; r < 4; ++r) {
            int row = m0 + wm + mt * 16 + quad * 4 + r;
            if (of32) {
                float* crow = (float*)Cout + (size_t)row * N + n0 + wn + l16;
                for (int nt = 0; nt < 4; ++nt)
                    crow[nt * 16] = acc[mt][nt][r];
            } else {
                u16* crow = (u16*)Cout + (size_t)row * N + n0 + wn + l16;
                for (int nt = 0; nt < 4; ++nt)
                    crow[nt * 16] = f2bf(acc[mt][nt][r]);
            }
        }
}

// ---------------- flash attention, causal + ALiBi ----------------
// qkv: [4096][3072] bf16 (Q=0..1023, K=1024..2047, V=2048..3071; feat=h*64+d).
// 64-row Q-blocks, 4 waves (wave owns 16 rows). K/V double-buffered + reg prefetch.
// KEY CHANGE (R7): S computed TRANSPOSED — mfma(A=K_frag, B=Q_frag) gives S^T in
// C-layout (col=l16=q-row, row=quad*4+r=key), so softmax rows live per-lane:
// max/sum are in-register over 16 values; only 2 cross-lane ops/kt (cross-quad max)
// + 4 alpha broadcasts. Ps stored [q][key] via 4x ds_write_b64. PV = mfma(Ps, Vt)
// lands O in the same C-layout as before. l-sum reduced once after the loop.
__global__ __launch_bounds__(256, 3)
void attn_k(const u16* qkv, u16* o, int ostride) {
    __shared__ alignas(16) u16 KsB [2][64 * 72];
    __shared__ alignas(16) u16 VtsB[2][64 * 72];
    __shared__ alignas(16) u16 Psh [64 * 72];          // [q(4 waves x 16)][key], stride 72
    const int x = blockIdx.x;
    const int qb = (x & 1) ? (31 - (x >> 1)) : (x >> 1);   // pair heavy+light blocks
    const int bh = blockIdx.y;
    const int b = bh >> 4, h = bh & 15;
    const int tid = threadIdx.x;
    const int wave = tid >> 6, lane = tid & 63;
    const int quad = lane >> 4, l16 = lane & 15;
    const float LOG2E = 1.44269504f;
    const float slope2 = exp2f(-0.5f * (float)(h + 1)) * LOG2E;
    const float scale2 = 0.125f * LOG2E;
    const size_t seq0 = (size_t)b * 2048;
    const int row0 = qb * 64 + wave * 16;          // wave's first Q row (block-seq coords)
    const int irow = row0 + l16;                   // this lane's softmax row (q = l16)

    // Q fragments in registers; used as MFMA *B* operand (B-frag: n=l16=qrow, k=quad*8+j)
    bf16x8 qf[2];
    {
        const u16* qrow = qkv + (seq0 + irow) * 3072 + h * 64;
        qf[0] = *(const bf16x8*)(qrow + quad * 8);
        qf[1] = *(const bf16x8*)(qrow + 32 + quad * 8);
    }

    float mst = -1e30f, lst = 0.f;     // per-lane: running max / PARTIAL sum for row q=l16
    f32x4 oacc[4];
    const f32x4 zero = {0.f, 0.f, 0.f, 0.f};
    for (int nt = 0; nt < 4; ++nt) oacc[nt] = zero;

    const int ktiles = qb + 1;
    const int c0 = tid * 2;
    const u16* kb0 = qkv + seq0 * 3072 + 1024 + h * 64;
    u16* PsW = &Psh[(wave * 16 + l16) * 72];       // this lane's Ps row (write base)

    // stage tile 0
    u16x8 kr[2], vr[2];
    for (int i = 0; i < 2; ++i) {
        int c = c0 + i;
        kr[i] = *(const u16x8*)(kb0 + (size_t)(c >> 3) * 3072 + (c & 7) * 8);
        vr[i] = *(const u16x8*)(kb0 + 1024 + (size_t)(c & 63) * 3072 + (c >> 6) * 8);
    }
    for (int i = 0; i < 2; ++i) {
        int c = c0 + i;
        *(u16x8*)&KsB[0][(c >> 3) * 72 + (c & 7) * 8] = kr[i];
        int key = c & 63, d0 = (c >> 6) * 8;
        for (int j = 0; j < 8; ++j) VtsB[0][(d0 + j) * 72 + key] = vr[i][j];
    }
    __syncthreads();

    for (int kt = 0; kt < ktiles; ++kt) {
        const int cur = kt & 1, nxt = cur ^ 1;
        const bool more = (kt + 1 < ktiles);
        if (more) {   // prefetch kt+1 into registers (lands during this iteration)
            const u16* kb = kb0 + (size_t)(kt + 1) * 64 * 3072;
            for (int i = 0; i < 2; ++i) {
                int c = c0 + i;
                kr[i] = *(const u16x8*)(kb + (size_t)(c >> 3) * 3072 + (c & 7) * 8);
                vr[i] = *(const u16x8*)(kb + 1024 + (size_t)(c & 63) * 3072 + (c >> 6) * 8);
            }
        }

        // S^T = K @ Q^T  (C-layout: col=l16=q, row=quad*4+r=key)
        f32x4 st[4];
        for (int nt = 0; nt < 4; ++nt) st[nt] = zero;
        for (int nt = 0; nt < 4; ++nt)
            for (int ks = 0; ks < 2; ++ks) {
                bf16x8 bk = *(const bf16x8*)&KsB[cur][(nt * 16 + l16) * 72 + ks * 32 + quad * 8];
                st[nt] = mfma16(bk, qf[ks], st[nt]);
            }

        // bias + causal (diag tile only), log2 domain.  key j = kt*64+nt*16+quad*4+r
        const int jbase = kt * 64 + quad * 4;
        if (kt == qb) {
            for (int nt = 0; nt < 4; ++nt)
                for (int r = 0; r < 4; ++r) {
                    int j = jbase + nt * 16 + r;
                    float v = st[nt][r] * scale2 + slope2 * (float)j;
                    st[nt][r] = (j <= irow) ? v : -1e30f;
                }
        } else {
            for (int nt = 0; nt < 4; ++nt)
                for (int r = 0; r < 4; ++r)
                    st[nt][r] = st[nt][r] * scale2 + slope2 * (float)(jbase + nt * 16 + r);
        }

        // in-register row max (16 values), then cross-quad reduce (2 shuffles)
        f32x4 mv = vmax4(vmax4(st[0], st[1]), vmax4(st[2], st[3]));
        float tm = fmaxf(fmaxf(mv[0], mv[1]), fmaxf(mv[2], mv[3]));
        tm = fmaxf(tm, __shfl_xor(tm, 16, 64));
        tm = fmaxf(tm, __shfl_xor(tm, 32, 64));
        float mnew = fmaxf(mst, tm);
        float alpha = exp2f(mst - mnew);
        mst = mnew;

        // p = exp2(s - m); per-lane partial sum (no cross-lane!)
        for (int nt = 0; nt < 4; ++nt)
            for (int r = 0; r < 4; ++r)
                st[nt][r] = exp2f(st[nt][r] - mnew);
        f32x4 sv = (st[0] + st[1]) + (st[2] + st[3]);
        lst = lst * alpha + ((sv[0] + sv[1]) + (sv[2] + sv[3]));

        // Ps[q=l16][key] <- packed bf16, one b64 per nt (keys quad*4+0..3)
        for (int nt = 0; nt < 4; ++nt) {
            u32x2 w;
            w[0] = (unsigned)bf16c(st[nt][0]) | ((unsigned)bf16c(st[nt][1]) << 16);
            w[1] = (unsigned)bf16c(st[nt][2]) | ((unsigned)bf16c(st[nt][3]) << 16);
            *(u32x2*)&PsW[nt * 16 + quad * 4] = w;
        }

        // O rescale: alpha for O-row quad*4+r lives in lane l16=quad*4+r (same group)
        float aO[4];
        for (int r = 0; r < 4; ++r) aO[r] = __shfl(alpha, quad * 4 + r, 16);
        for (int nt = 0; nt < 4; ++nt)
            for (int r = 0; r < 4; ++r) oacc[nt][r] *= aO[r];

        // O += P @ V  (A = Ps rows [q=l16], B = Vt rows; intra-wave Ps, in-order DS)
        bf16x8 ap[2];
        ap[0] = *(const bf16x8*)&Psh[(wave * 16 + l16) * 72 + quad * 8];
        ap[1] = *(const bf16x8*)&Psh[(wave * 16 + l16) * 72 + 32 + quad * 8];
        for (int nt = 0; nt < 4; ++nt)
            for (int ks = 0; ks < 2; ++ks) {
                bf16x8 bv = *(const bf16x8*)&VtsB[cur][(nt * 16 + l16) * 72 + ks * 32 + quad * 8];
                oacc[nt] = mfma16(ap[ks], bv, oacc[nt]);
            }

        if (more) {   // publish kt+1 tiles into the other buffer
            for (int i = 0; i < 2; ++i) {
                int c = c0 + i;
                *(u16x8*)&KsB[nxt][(c >> 3) * 72 + (c & 7) * 8] = kr[i];
                int key = c & 63, d0 = (c >> 6) * 8;
                for (int j = 0; j < 8; ++j) VtsB[nxt][(d0 + j) * 72 + key] = vr[i][j];
            }
        }
        __syncthreads();   // publish nxt K/V
    }

    // final l: reduce partials across the 4 quads (per row q=l16), then gather 1/l
    float l2 = lst + __shfl_xor(lst, 16, 64);
    float l4 = l2 + __shfl_xor(l2, 32, 64);
    float inv = 1.f / l4;
    for (int r = 0; r < 4; ++r) {
        float invO = __shfl(inv, quad * 4 + r, 16);
        int il = qb * 64 + wave * 16 + quad * 4 + r;
        u16* orow = o + (seq0 + il) * (size_t)ostride + h * 64 + l16;
        for (int nt = 0; nt < 4; ++nt)
            orow[nt * 16] = bf16c(oacc[nt][r] * invO);
    }
}

// ---------------- launch ----------------
// Inputs fp32, output fp32. Workspace peak 30 MiB:
//   ws+256: wqkvT [3072][1024] bf16 6 MiB (reused for wprojT) | qkv [4096][3072] 24 MiB.
// x's bf16 copy uses the first 8 MiB of d_out (dead before gemm2 writes all 16 MiB).
extern "C" void kernel_launch(void* const* d_in, const int* in_sizes, int n_in,
                              void* d_out, int out_size, void* d_ws, size_t ws_size,
                              hipStream_t stream) {
    (void)in_sizes; (void)n_in; (void)out_size; (void)ws_size;
    const float* x     = (const float*)d_in[0];   // [4096][1024]
    const float* wqkv  = (const float*)d_in[1];   // [1024][3072]
    const float* wproj = (const float*)d_in[2];   // [1024][1024]

    char* ws = (char*)d_ws;
    u16* wqkvT  = (u16*)(ws + 256);
    u16* wprojT = wqkvT;                               // reused after gemm1
    u16* qkv    = wqkvT + (size_t)3072 * 1024;
    u16* xb     = (u16*)d_out;                         // scratch in d_out

    cvt_k<<<dim3(2048), 256, 0, stream>>>(x, xb, 4096 * 1024 / 8);
    transpose_cvt_k<<<dim3(48, 16), 256, 0, stream>>>(wqkv, wqkvT, 1024, 3072);

    gemm_bt<<<dim3(32, 24), 256, 0, stream>>>(xb, wqkvT, qkv, 4096, 3072, 1024, 1024, 0);

    transpose_cvt_k<<<dim3(16, 16), 256, 0, stream>>>(wproj, wprojT, 1024, 1024);

    attn_k<<<dim3(32, 32), 256, 0, stream>>>(qkv, qkv, 3072);   // out -> Q region

    gemm_bt<<<dim3(32, 8), 256, 0, stream>>>(qkv, wprojT, d_out, 4096, 1024, 1024, 3072, 1);
}

// Round 8
// 186.627 us; speedup vs baseline: 1.5999x; 1.3546x over previous
//
#include <hip/hip_runtime.h>
#include <cstdint>
#include <cstddef>

typedef unsigned short u16;
typedef __bf16 bf16x8 __attribute__((ext_vector_type(8)));
typedef float f32x4 __attribute__((ext_vector_type(4)));
typedef u16 u16x4 __attribute__((ext_vector_type(4)));
typedef u16 u16x8 __attribute__((ext_vector_type(8)));
typedef unsigned int u32x2 __attribute__((ext_vector_type(2)));
typedef unsigned int u32x4 __attribute__((ext_vector_type(4)));

#define DEV __device__ __forceinline__

DEV u16 f2bf(float f) {
    union { float f; unsigned u; } un; un.f = f;
    unsigned u = un.u;
    return (u16)((u + 0x7fffu + ((u >> 16) & 1u)) >> 16);
}

DEV u16 bf16c(float f) {            // HW convert (RNE)
    __bf16 b = (__bf16)f;
    u16 r; __builtin_memcpy(&r, &b, 2); return r;
}

DEV f32x4 mfma16(bf16x8 a, bf16x8 b, f32x4 c) {
    return __builtin_amdgcn_mfma_f32_16x16x32_bf16(a, b, c, 0, 0, 0);
}

DEV f32x4 vmax4(f32x4 a, f32x4 b) {
    f32x4 r;
    r[0] = fmaxf(a[0], b[0]); r[1] = fmaxf(a[1], b[1]);
    r[2] = fmaxf(a[2], b[2]); r[3] = fmaxf(a[3], b[3]);
    return r;
}

// async global->LDS, 16B per lane; lds dest is wave-uniform base (+lane*16 implicit)
DEV void async16(const u16* g, u16* l) {
    __builtin_amdgcn_global_load_lds(
        (__attribute__((address_space(1))) unsigned int*)(void*)g,
        (__attribute__((address_space(3))) unsigned int*)(void*)l,
        16, 0, 0);
}

// ---------------- fp32 -> bf16 cast (x), 8 elems/thread ----------------
__global__ __launch_bounds__(256)
void cvt_k(const float* __restrict__ src, u16* __restrict__ dst, int n8) {
    int i = blockIdx.x * 256 + threadIdx.x;
    if (i >= n8) return;
    const float* s = src + (size_t)i * 8;
    f32x4 a = *(const f32x4*)s;
    f32x4 b = *(const f32x4*)(s + 4);
    u16x8 o;
    o[0] = f2bf(a[0]); o[1] = f2bf(a[1]); o[2] = f2bf(a[2]); o[3] = f2bf(a[3]);
    o[4] = f2bf(b[0]); o[5] = f2bf(b[1]); o[6] = f2bf(b[2]); o[7] = f2bf(b[3]);
    *(u16x8*)(dst + (size_t)i * 8) = o;
}

// ---------------- fp32 src[R][C] -> bf16 dst[C][R] ----------------
__global__ __launch_bounds__(256)
void transpose_cvt_k(const float* __restrict__ src, u16* __restrict__ dst, int R, int C) {
    __shared__ u16 t[64][65];
    const int tid = threadIdx.x;
    const int c0 = blockIdx.x * 64, r0 = blockIdx.y * 64;
    for (int i = 0; i < 4; ++i) {
        int e = (i * 256 + tid) * 4;
        int r = e >> 6, c = e & 63;
        f32x4 v = *(const f32x4*)(src + (size_t)(r0 + r) * C + (c0 + c));
        t[r][c] = f2bf(v[0]); t[r][c + 1] = f2bf(v[1]);
        t[r][c + 2] = f2bf(v[2]); t[r][c + 3] = f2bf(v[3]);
    }
    __syncthreads();
    for (int i = 0; i < 4; ++i) {
        int e = (i * 256 + tid) * 4;
        int ro = e >> 6, co = e & 63;
        u16x4 v;
        v[0] = t[co][ro]; v[1] = t[co + 1][ro]; v[2] = t[co + 2][ro]; v[3] = t[co + 3][ro];
        *(u16x4*)(dst + (size_t)(c0 + ro) * R + (r0 + co)) = v;
    }
}

// ---------------- C[M][N] = A[M][K] @ Bt[N][K]^T, bf16 in, fp32 acc ----------------
__global__ __launch_bounds__(256, 2)
void gemm_bt(const u16* __restrict__ A, const u16* __restrict__ Bt,
             void* __restrict__ Cout, int M, int N, int K, int lda, int of32) {
    __shared__ alignas(16) u16 As[128 * 32];
    __shared__ alignas(16) u16 Bs[128 * 32];
    const int tid = threadIdx.x;
    const int wave = tid >> 6, lane = tid & 63;
    const int quad = lane >> 4, l16 = lane & 15;
    const int m0 = blockIdx.x * 128, n0 = blockIdx.y * 128;
    const int wm = (wave & 1) * 64, wn = (wave >> 1) * 64;

    const f32x4 zero = {0.f, 0.f, 0.f, 0.f};
    f32x4 acc[4][4];
    for (int i = 0; i < 4; ++i) for (int j = 0; j < 4; ++j) acc[i][j] = zero;

    for (int k0 = 0; k0 < K; k0 += 32) {
        __syncthreads();
        for (int p = 0; p < 2; ++p) {
            int s = p * 256 + tid;
            int row = s >> 2, kcs = s & 3;
            int kc = kcs ^ ((row >> 1) & 3);
            async16(A + (size_t)(m0 + row) * lda + k0 + kc * 8, &As[(p * 256 + wave * 64) * 8]);
            async16(Bt + (size_t)(n0 + row) * K + k0 + kc * 8, &Bs[(p * 256 + wave * 64) * 8]);
        }
        __syncthreads();

        bf16x8 af[4], bfr[4];
        for (int mt = 0; mt < 4; ++mt) {
            int row = wm + mt * 16 + l16;
            int ci = (row << 2) | (quad ^ ((row >> 1) & 3));
            af[mt] = *(const bf16x8*)&As[ci * 8];
        }
        for (int nt = 0; nt < 4; ++nt) {
            int col = wn + nt * 16 + l16;
            int ci = (col << 2) | (quad ^ ((col >> 1) & 3));
            bfr[nt] = *(const bf16x8*)&Bs[ci * 8];
        }
        for (int mt = 0; mt < 4; ++mt)
            for (int nt = 0; nt < 4; ++nt)
                acc[mt][nt] = mfma16(af[mt], bfr[nt], acc[mt][nt]);
    }

    for (int mt = 0; mt < 4; ++mt)
        for (int r = 0; r < 4; ++r) {
            int row = m0 + wm + mt * 16 + quad * 4 + r;
            if (of32) {
                float* crow = (float*)Cout + (size_t)row * N + n0 + wn + l16;
                for (int nt = 0; nt < 4; ++nt)
                    crow[nt * 16] = acc[mt][nt][r];
            } else {
                u16* crow = (u16*)Cout + (size_t)row * N + n0 + wn + l16;
                for (int nt = 0; nt < 4; ++nt)
                    crow[nt * 16] = f2bf(acc[mt][nt][r]);
            }
        }
}

// ---------------- flash attention, causal + ALiBi ----------------
// R8 structure:
//  * S^T = mfma(K,Q): softmax rows per-lane (q = l16).
//  * O^T = mfma(Vt, Ps): C-layout col = l16 = q -> alpha rescale and 1/l fully
//    per-lane (no cross-lane gathers). Epilogue: lane q writes d-chunks (b64 packs).
//  * LDS stride 64 with XOR swizzle (16B chunk ^= row&7): Ks/Vts dbuf + Psh = 40 KB
//    -> 4 blocks/CU. Conflicts <=2-way everywhere.
//  * K staged by swizzled global_load_lds (DMA); V by paired-key b32 writes.
//  * LPT grid: heaviest q-blocks dispatched first.
__global__ __launch_bounds__(256, 4)
void attn_k(const u16* qkv, u16* o, int ostride) {
    __shared__ alignas(16) u16 KsB [2][64 * 64];
    __shared__ alignas(16) u16 VtsB[2][64 * 64];
    __shared__ alignas(16) u16 Psh [64 * 64];
    const int x = blockIdx.x;
    const int qb = 31 - (x >> 5);          // heavy blocks first (LPT)
    const int bh = x & 31;
    const int b = bh >> 4, h = bh & 15;
    const int tid = threadIdx.x;
    const int wave = tid >> 6, lane = tid & 63;
    const int quad = lane >> 4, l16 = lane & 15;
    const float LOG2E = 1.44269504f;
    const float slope2 = exp2f(-0.5f * (float)(h + 1)) * LOG2E;
    const float scale2 = 0.125f * LOG2E;
    const size_t seq0 = (size_t)b * 2048;
    const int row0 = qb * 64 + wave * 16;
    const int irow = row0 + l16;           // this lane's softmax row (q = l16)

    // Q fragments (MFMA B operand for S^T: n=l16=q, k=quad*8+j)
    bf16x8 qf[2];
    {
        const u16* qrow = qkv + (seq0 + irow) * 3072 + h * 64;
        qf[0] = *(const bf16x8*)(qrow + quad * 8);
        qf[1] = *(const bf16x8*)(qrow + 32 + quad * 8);
    }

    // hoisted ALiBi bias for this lane's 16 (nt,r) slots (kt-invariant part)
    float pre[4][4];
    for (int nt = 0; nt < 4; ++nt)
        for (int r = 0; r < 4; ++r)
            pre[nt][r] = slope2 * (float)(nt * 16 + quad * 4 + r);

    float mst = -1e30f, lst = 0.f;         // per-lane running max / partial sum
    f32x4 oacc[4];                          // O^T: col q=l16, row d=nt*16+quad*4+r
    const f32x4 zero = {0.f, 0.f, 0.f, 0.f};
    for (int nt = 0; nt < 4; ++nt) oacc[nt] = zero;

    const int ktiles = qb + 1;
    const u16* kbase = qkv + seq0 * 3072 + 1024 + h * 64;
    const u16* vbase = kbase + 1024;
    const int tpair = tid & 31;            // V pair word index within row
    const int vd0 = ((tid * 2) >> 6) * 8;  // V d-chunk base for this thread
    const int k0p = (tid * 2) & 63;        // first of the thread's key pair

    // ---- stage tile 0 ----
    for (int p = 0; p < 2; ++p) {          // K via swizzled DMA
        int row = wave * 16 + p * 8 + (lane >> 3);
        int kc = (lane & 7) ^ (row & 7);
        async16(kbase + (size_t)row * 3072 + kc * 8, &KsB[0][(wave * 16 + p * 8) * 64]);
    }
    u16x8 vr0, vr1;
    vr0 = *(const u16x8*)(vbase + (size_t)k0p * 3072 + vd0);
    vr1 = *(const u16x8*)(vbase + (size_t)(k0p + 1) * 3072 + vd0);
    for (int j = 0; j < 8; ++j) {
        unsigned w = (unsigned)vr0[j] | ((unsigned)vr1[j] << 16);
        int d = vd0 + j;
        *(unsigned*)&VtsB[0][d * 64 + (((tpair >> 2) ^ (d & 7)) << 3) + (tpair & 3) * 2] = w;
    }
    __syncthreads();

    for (int kt = 0; kt < ktiles; ++kt) {
        const int cur = kt & 1, nxt = cur ^ 1;
        const bool more = (kt + 1 < ktiles);
        if (more) {    // K DMA straight into nxt; V into registers
            const u16* kb = kbase + (size_t)(kt + 1) * 64 * 3072;
            for (int p = 0; p < 2; ++p) {
                int row = wave * 16 + p * 8 + (lane >> 3);
                int kc = (lane & 7) ^ (row & 7);
                async16(kb + (size_t)row * 3072 + kc * 8, &KsB[nxt][(wave * 16 + p * 8) * 64]);
            }
            const u16* vb = vbase + (size_t)(kt + 1) * 64 * 3072;
            vr0 = *(const u16x8*)(vb + (size_t)k0p * 3072 + vd0);
            vr1 = *(const u16x8*)(vb + (size_t)(k0p + 1) * 3072 + vd0);
        }

        // S^T = K @ Q^T (C-layout: col=l16=q, row=quad*4+r=key within nt*16 group)
        f32x4 st[4];
        for (int nt = 0; nt < 4; ++nt) st[nt] = zero;
        for (int nt = 0; nt < 4; ++nt)
            for (int ks = 0; ks < 2; ++ks) {
                int krow = nt * 16 + l16;
                bf16x8 bk = *(const bf16x8*)&KsB[cur][krow * 64 + (((ks * 4 + quad) ^ (krow & 7)) << 3)];
                st[nt] = mfma16(bk, qf[ks], st[nt]);
            }

        // bias (biased domain: true score = st*scale2 + pre + b0, b0 = slope2*64*kt)
        const float b0 = slope2 * (float)(kt * 64);
        for (int nt = 0; nt < 4; ++nt)
            for (int r = 0; r < 4; ++r)
                st[nt][r] = st[nt][r] * scale2 + pre[nt][r];
        if (kt == qb) {    // causal mask, diagonal tile only
            const int loc = irow - kt * 64;     // key_local <= loc
            for (int nt = 0; nt < 4; ++nt)
                for (int r = 0; r < 4; ++r)
                    st[nt][r] = (nt * 16 + quad * 4 + r <= loc) ? st[nt][r] : -1e30f;
        }

        // row max: 16 in-register + 2 cross-quad shuffles
        f32x4 mv = vmax4(vmax4(st[0], st[1]), vmax4(st[2], st[3]));
        float tm = fmaxf(fmaxf(mv[0], mv[1]), fmaxf(mv[2], mv[3]));
        tm = fmaxf(tm, __shfl_xor(tm, 16, 64));
        tm = fmaxf(tm, __shfl_xor(tm, 32, 64));
        float mnew = fmaxf(mst, tm + b0);       // true-domain running max
        float alpha = exp2f(mst - mnew);
        mst = mnew;
        const float dsub = mnew - b0;           // subtract in biased domain

        for (int nt = 0; nt < 4; ++nt)
            for (int r = 0; r < 4; ++r)
                st[nt][r] = exp2f(st[nt][r] - dsub);
        f32x4 sv = (st[0] + st[1]) + (st[2] + st[3]);
        lst = lst * alpha + ((sv[0] + sv[1]) + (sv[2] + sv[3]));

        // Ps[q][k] <- packed bf16 b64 per nt (intra-wave rows, no barrier needed)
        {
            const int q = wave * 16 + l16;
            for (int nt = 0; nt < 4; ++nt) {
                u32x2 w;
                w[0] = (unsigned)bf16c(st[nt][0]) | ((unsigned)bf16c(st[nt][1]) << 16);
                w[1] = (unsigned)bf16c(st[nt][2]) | ((unsigned)bf16c(st[nt][3]) << 16);
                int ch = ((nt * 2 + (quad >> 1)) ^ (l16 & 7));
                *(u32x2*)&Psh[q * 64 + (ch << 3) + (quad & 1) * 4] = w;
            }
        }

        // per-lane O^T rescale (alpha is for q = l16 — this lane's column!)
        for (int nt = 0; nt < 4; ++nt)
            for (int r = 0; r < 4; ++r) oacc[nt][r] *= alpha;

        // O^T += mfma(A=Vt rows d, B=Ps rows q)
        {
            const int q = wave * 16 + l16;
            bf16x8 ap[2];
            ap[0] = *(const bf16x8*)&Psh[q * 64 + (((quad) ^ (l16 & 7)) << 3)];
            ap[1] = *(const bf16x8*)&Psh[q * 64 + (((4 + quad) ^ (l16 & 7)) << 3)];
            for (int nt = 0; nt < 4; ++nt) {
                int drow = nt * 16 + l16;
                for (int ks = 0; ks < 2; ++ks) {
                    bf16x8 av = *(const bf16x8*)&VtsB[cur][drow * 64 + (((ks * 4 + quad) ^ (drow & 7)) << 3)];
                    oacc[nt] = mfma16(av, ap[ks], oacc[nt]);
                }
            }
        }

        if (more) {    // publish V pairs into nxt
            for (int j = 0; j < 8; ++j) {
                unsigned w = (unsigned)vr0[j] | ((unsigned)vr1[j] << 16);
                int d = vd0 + j;
                *(unsigned*)&VtsB[nxt][d * 64 + (((tpair >> 2) ^ (d & 7)) << 3) + (tpair & 3) * 2] = w;
            }
        }
        __syncthreads();    // publish nxt K (DMA drained) + V; guard cur reuse
    }

    // final l across quads (per-lane), then write O[q][d] (lane q = l16)
    float l2 = lst + __shfl_xor(lst, 16, 64);
    float l4 = l2 + __shfl_xor(l2, 32, 64);
    float inv = 1.f / l4;
    u16* orow = o + (seq0 + row0 + l16) * (size_t)ostride + h * 64 + quad * 4;
    for (int nt = 0; nt < 4; ++nt) {
        u16x4 w;
        for (int r = 0; r < 4; ++r) w[r] = bf16c(oacc[nt][r] * inv);
        *(u16x4*)(orow + nt * 16) = w;
    }
}

// ---------------- launch ----------------
// Inputs fp32, output fp32. Workspace peak 30 MiB:
//   ws+256: wqkvT 6 MiB (reused for wprojT) | qkv [4096][3072] bf16 24 MiB.
// x's bf16 copy lives in d_out's first 8 MiB (dead before gemm2 writes).
extern "C" void kernel_launch(void* const* d_in, const int* in_sizes, int n_in,
                              void* d_out, int out_size, void* d_ws, size_t ws_size,
                              hipStream_t stream) {
    (void)in_sizes; (void)n_in; (void)out_size; (void)ws_size;
    const float* x     = (const float*)d_in[0];   // [4096][1024]
    const float* wqkv  = (const float*)d_in[1];   // [1024][3072]
    const float* wproj = (const float*)d_in[2];   // [1024][1024]

    char* ws = (char*)d_ws;
    u16* wqkvT  = (u16*)(ws + 256);
    u16* wprojT = wqkvT;
    u16* qkv    = wqkvT + (size_t)3072 * 1024;
    u16* xb     = (u16*)d_out;

    cvt_k<<<dim3(2048), 256, 0, stream>>>(x, xb, 4096 * 1024 / 8);
    transpose_cvt_k<<<dim3(48, 16), 256, 0, stream>>>(wqkv, wqkvT, 1024, 3072);

    gemm_bt<<<dim3(32, 24), 256, 0, stream>>>(xb, wqkvT, qkv, 4096, 3072, 1024, 1024, 0);

    transpose_cvt_k<<<dim3(16, 16), 256, 0, stream>>>(wproj, wprojT, 1024, 1024);

    attn_k<<<dim3(1024), 256, 0, stream>>>(qkv, qkv, 3072);   // out -> Q region

    gemm_bt<<<dim3(32, 8), 256, 0, stream>>>(qkv, wprojT, d_out, 4096, 1024, 1024, 3072, 1);
}